// Round 11
// baseline (129.867 us; speedup 1.0000x reference)
//
#include <hip/hip_runtime.h>
#include <hip/hip_bf16.h>
#include <math.h>

typedef __attribute__((ext_vector_type(8))) short short8;
typedef __attribute__((ext_vector_type(2))) unsigned int uint2v;
typedef __attribute__((ext_vector_type(4))) float f32x4;
typedef __attribute__((ext_vector_type(4))) float float4v;
typedef __attribute__((ext_vector_type(4))) unsigned short ushort4v;

typedef __attribute__((address_space(1))) const unsigned int GAS;
typedef __attribute__((address_space(3))) unsigned int LAS;

#define B_ 4
#define S_ 4096
#define D_ 128

// geometry: q-tile = 128 rows (4 waves x 2 col-groups x 16), kv-tile = 64 keys, chunk = 4 kv-tiles
// per batch: qt needs kv tiles 0..2qt+1; nc(qt) = ceil((qt+1)/2); CPB = 272
#define CPB 272
#define NSLOT (B_ * CPB)   // 1088 partial slots, 128 rows each (32KB)

// LDS layout (bytes): K 16K | V 16K | P 4 waves x 2 cg x 2K = 16K  => 48KB, 3 blocks/CU
#define LDS_K 0
#define LDS_V 16384
#define LDS_P 32768
#define LDS_TOTAL 49152

__device__ __forceinline__ unsigned short f2bf(float f) {
    union { float f; unsigned u; } v; v.f = f;
    unsigned r = v.u + 0x7FFFu + ((v.u >> 16) & 1u);
    return (unsigned short)(r >> 16);
}
__device__ __forceinline__ float bf2f(unsigned short h) {
    union { unsigned u; float f; } v; v.u = ((unsigned)h) << 16;
    return v.f;
}
__device__ __forceinline__ unsigned cvt_pk_bf16(float lo, float hi) {
    unsigned r;
    asm("v_cvt_pk_bf16_f32 %0, %1, %2" : "=v"(r) : "v"(lo), "v"(hi));
    return r;
}

// ---------------- kernel 0: W -> bf16, concat [Wq;Wk;Wv] as [384][128] ----------------
__global__ void wconv_kernel(const float* __restrict__ Wq,
                             const float* __restrict__ Wk,
                             const float* __restrict__ Wv,
                             unsigned short* __restrict__ Wb) {
    int i = blockIdx.x * 256 + threadIdx.x;
    if (i >= 3 * 16384) return;
    const float* s = (i < 16384) ? Wq : (i < 32768 ? Wk : Wv);
    Wb[i] = f2bf(s[i & 16383]);
}

// ---------------- kernel 1: QKV projection (log2e/sqrt(D) folded into Q) ----------------
__global__ __launch_bounds__(256) void qkv_kernel(const float* __restrict__ X,
                                                  const unsigned short* __restrict__ Wb,
                                                  unsigned short* __restrict__ Qb,
                                                  unsigned short* __restrict__ Kb,
                                                  unsigned short* __restrict__ Vt) {
    const int tid = threadIdx.x;
    const int lane = tid & 63, w = tid >> 6;
    const int l16 = lane & 15, g = lane >> 4;
    const int r0 = blockIdx.x * 64;
    const int grp = blockIdx.y;

    const int row = r0 + w * 16 + l16;
    const float* xr = X + (long)row * 128;
    float4v x0[4], x1[4];
    #pragma unroll
    for (int kb = 0; kb < 4; ++kb) {
        x0[kb] = *reinterpret_cast<const float4v*>(xr + kb * 32 + g * 8);
        x1[kb] = *reinterpret_cast<const float4v*>(xr + kb * 32 + g * 8 + 4);
    }
    short8 a[4];
    #pragma unroll
    for (int kb = 0; kb < 4; ++kb) {
        short8 t;
        t[0] = f2bf(x0[kb][0]); t[1] = f2bf(x0[kb][1]);
        t[2] = f2bf(x0[kb][2]); t[3] = f2bf(x0[kb][3]);
        t[4] = f2bf(x1[kb][0]); t[5] = f2bf(x1[kb][1]);
        t[6] = f2bf(x1[kb][2]); t[7] = f2bf(x1[kb][3]);
        a[kb] = t;
    }

    const float scale = 0.12751744416006513f; // log2(e)/sqrt(128): scores in log2 domain
    #pragma unroll
    for (int ct = 0; ct < 8; ++ct) {
        const int e = ct * 16 + l16;
        const int c = grp * 128 + e;
        f32x4 acc = {0.f, 0.f, 0.f, 0.f};
        #pragma unroll
        for (int kb = 0; kb < 4; ++kb) {
            short8 bf = *reinterpret_cast<const short8*>(Wb + (long)c * 128 + kb * 32 + g * 8);
            acc = __builtin_amdgcn_mfma_f32_16x16x32_bf16(a[kb], bf, acc, 0, 0, 0);
        }
        const int row0 = r0 + w * 16 + g * 4;
        if (grp == 0) {
            #pragma unroll
            for (int r = 0; r < 4; ++r) Qb[(long)(row0 + r) * 128 + e] = f2bf(acc[r] * scale);
        } else if (grp == 1) {
            #pragma unroll
            for (int r = 0; r < 4; ++r) Kb[(long)(row0 + r) * 128 + e] = f2bf(acc[r]);
        } else {
            const int bb = row0 >> 12, ss = row0 & 4095;
            ushort4v p;
            p[0] = f2bf(acc[0]); p[1] = f2bf(acc[1]); p[2] = f2bf(acc[2]); p[3] = f2bf(acc[3]);
            *reinterpret_cast<ushort4v*>(&Vt[((long)bb * 128 + e) * 4096 + ss]) = p;
        }
    }
}

// ---------------- kernel 2: split-KV flash attention, 128-row q-tile / 2 col-groups ----------------
// Swapped QK^T (lane owns one q-row per cg); K/V fragment reads SHARED across both cgs.
// cg0 fully masked on tile kt==2qt+1 -> skipped entirely (wave-uniform).
__global__ __launch_bounds__(256, 3) void attn_kernel(const unsigned short* __restrict__ Qb,
                                                      const unsigned short* __restrict__ Kb,
                                                      const unsigned short* __restrict__ Vt,
                                                      unsigned short* __restrict__ Opart,
                                                      float* __restrict__ Mpart,
                                                      float* __restrict__ Lpart) {
    __shared__ __align__(16) unsigned char lds[LDS_TOTAL];

    const int tid = threadIdx.x;
    const int lane = tid & 63, w = tid >> 6;
    const int l16 = lane & 15, g = lane >> 4;

    // block -> (b, qt, c): rr = S(qt)+c, S(2h)=h(h+1), S(2h+1)=(h+1)^2 (r7-verified mapping)
    const int bidx = (int)blockIdx.x;
    const int b = bidx / CPB;
    const int rr = CPB - 1 - (bidx - b * CPB);   // reversed: longest blocks first
    int h = 0;
    while ((h + 1) * (h + 2) <= rr) ++h;
    int qt, c;
    {
        int rem = rr - h * (h + 1);
        if (rem < h + 1) { qt = 2 * h; c = rem; }
        else             { qt = 2 * h + 1; c = rr - (h + 1) * (h + 1); }
    }
    const int slot = b * CPB + rr;

    const unsigned short* Qbase = Qb + (long)b * S_ * D_;
    const unsigned char* Kb_b = (const unsigned char*)(Kb + (long)b * S_ * D_);
    const unsigned char* Vb_b = (const unsigned char*)(Vt + (long)b * D_ * S_);

    // Q fragments for both col-groups (pre-scaled; B-operand col = l16 = q-row)
    short8 qf[2][4];
    #pragma unroll
    for (int cg = 0; cg < 2; ++cg) {
        const long qrow = qt * 128 + cg * 64 + w * 16 + l16;
        #pragma unroll
        for (int kb = 0; kb < 4; ++kb)
            qf[cg][kb] = *reinterpret_cast<const short8*>(Qbase + qrow * 128 + kb * 32 + g * 8);
    }

    // pre-swizzled global source offsets for DMA staging (XOR involution, verified r4..r10)
    int koff[4], voff[4];
    #pragma unroll
    for (int i = 0; i < 4; ++i) {
        int ch = i * 256 + tid;
        int krow = ch >> 4, kcd = ch & 15;
        koff[i] = krow * 256 + ((kcd * 16) ^ ((krow & 7) << 4));
        int vrow = ch >> 3, vck = ch & 7;
        voff[i] = vrow * 8192 + ((vck * 16) ^ ((vrow & 7) << 4));
    }

    // hoisted swizzled LDS addresses
    const int swz = (l16 & 7) << 4;
    const unsigned char* kaddr[4];   // K A-frag: row = ct*16+l16; +ct*4096 imm
    const unsigned char* vaddr[2];   // V B-frag: d-row = dt*16+l16; +dt*2048 imm
    unsigned char* Pw = lds + LDS_P + w * 4096;
    const unsigned char* pread[2][2];
    unsigned char* pwrite[2][4];
    #pragma unroll
    for (int i = 0; i < 4; ++i)
        kaddr[i] = lds + LDS_K + l16 * 256 + ((i * 64 + g * 16) ^ swz);
    #pragma unroll
    for (int i = 0; i < 2; ++i)
        vaddr[i] = lds + LDS_V + l16 * 128 + ((i * 64 + g * 16) ^ swz);
    #pragma unroll
    for (int cg = 0; cg < 2; ++cg) {
        #pragma unroll
        for (int i = 0; i < 2; ++i)
            pread[cg][i] = Pw + cg * 2048 + l16 * 128 + ((i * 64 + g * 16) ^ swz);
        #pragma unroll
        for (int i = 0; i < 4; ++i)
            pwrite[cg][i] = Pw + cg * 2048 + l16 * 128 + ((i * 32 + g * 8) ^ swz);
    }

    f32x4 o[2][8];
    #pragma unroll
    for (int cg = 0; cg < 2; ++cg)
        #pragma unroll
        for (int dt = 0; dt < 8; ++dt) o[cg][dt] = (f32x4){0.f, 0.f, 0.f, 0.f};
    float m[2] = {-INFINITY, -INFINITY}, lsum[2] = {0.f, 0.f};
    const int myql = w * 16 + l16;            // local q-row within cg

    const int kt0 = c * 4;
    const int ktend = min(kt0 + 3, 2 * qt + 1);

    for (int kt = kt0; kt <= ktend; ++kt) {
        // ---- DMA this tile's K and V into LDS ----
        #pragma unroll
        for (int i = 0; i < 4; ++i) {
            int ch = i * 256 + tid;
            __builtin_amdgcn_global_load_lds((GAS*)(Kb_b + (long)kt * 16384 + koff[i]),
                                             (LAS*)(lds + LDS_K + ch * 16), 16, 0, 0);
            __builtin_amdgcn_global_load_lds((GAS*)(Vb_b + (long)kt * 128 + voff[i]),
                                             (LAS*)(lds + LDS_V + ch * 16), 16, 0, 0);
        }
        __syncthreads();   // vmcnt(0) drain + barrier: tile resident

        const int ktl = kt - 2 * qt;   // >= -? ; ktl==1 means last diagonal tile
        #pragma unroll
        for (int cg = 0; cg < 2; ++cg) {
            if (cg == 0 && ktl == 1) continue;   // fully masked tile for cg0: skip all

            // ---- S^T = K Q^T : lane gets S[k=ct*16+g*4+r][q = cg*64 + w*16 + l16] ----
            f32x4 s[4];
            __builtin_amdgcn_s_setprio(1);
            #pragma unroll
            for (int ct = 0; ct < 4; ++ct) {
                s[ct] = (f32x4){0.f, 0.f, 0.f, 0.f};
                #pragma unroll
                for (int kb = 0; kb < 4; ++kb) {
                    short8 kf = *reinterpret_cast<const short8*>(kaddr[kb] + ct * 4096);
                    s[ct] = __builtin_amdgcn_mfma_f32_16x16x32_bf16(kf, qf[cg][kb], s[ct], 0, 0, 0);
                }
            }
            __builtin_amdgcn_s_setprio(0);

            // ---- causal mask: only diagonal tiles (wave-uniform branch) ----
            if (ktl >= 0) {
                const int qloc = cg * 64 + myql;
                #pragma unroll
                for (int ct = 0; ct < 4; ++ct) {
                    const int kloc = ktl * 64 + ct * 16 + g * 4;
                    #pragma unroll
                    for (int r = 0; r < 4; ++r)
                        if (kloc + r > qloc) s[ct][r] = -1e30f;
                }
            }

            // ---- online softmax (log2 domain), scalar m/lsum, defer-rescale (T13) ----
            float rmax = s[0][0];
            #pragma unroll
            for (int ct = 0; ct < 4; ++ct) {
                #pragma unroll
                for (int r = 0; r < 4; ++r) rmax = fmaxf(rmax, s[ct][r]);
            }
            rmax = fmaxf(rmax, __shfl_xor(rmax, 16, 64));
            rmax = fmaxf(rmax, __shfl_xor(rmax, 32, 64));
            if (__any(rmax > m[cg] + 11.5f)) {      // 2^11.5 ~ e^8 headroom
                float mn = fmaxf(m[cg], rmax);
                float al = exp2f(m[cg] - mn);
                m[cg] = mn;
                lsum[cg] *= al;
                #pragma unroll
                for (int dt = 0; dt < 8; ++dt) {
                    #pragma unroll
                    for (int r = 0; r < 4; ++r) o[cg][dt][r] *= al;
                }
            }
            float rsum = 0.f;
            #pragma unroll
            for (int ct = 0; ct < 4; ++ct) {
                #pragma unroll
                for (int r = 0; r < 4; ++r) {
                    float p = exp2f(s[ct][r] - m[cg]);
                    s[ct][r] = p;
                    rsum += p;
                }
            }
            rsum += __shfl_xor(rsum, 16, 64);
            rsum += __shfl_xor(rsum, 32, 64);
            lsum[cg] += rsum;

            // ---- P -> per-wave LDS: cvt_pk pairs, 4x ds_write_b64 ----
            #pragma unroll
            for (int ct = 0; ct < 4; ++ct) {
                uint2v pb;
                pb[0] = cvt_pk_bf16(s[ct][0], s[ct][1]);
                pb[1] = cvt_pk_bf16(s[ct][2], s[ct][3]);
                *reinterpret_cast<uint2v*>(pwrite[cg][ct]) = pb;
            }

            // ---- O += P V (V fragment reads shared-layout; 16x16x32, P as A-frag) ----
            #pragma unroll
            for (int kvb = 0; kvb < 2; ++kvb) {
                short8 pf = *reinterpret_cast<const short8*>(pread[cg][kvb]);
                __builtin_amdgcn_s_setprio(1);
                #pragma unroll
                for (int dt = 0; dt < 8; ++dt) {
                    short8 vf = *reinterpret_cast<const short8*>(vaddr[kvb] + dt * 2048);
                    o[cg][dt] = __builtin_amdgcn_mfma_f32_16x16x32_bf16(pf, vf, o[cg][dt], 0, 0, 0);
                }
                __builtin_amdgcn_s_setprio(0);
            }
        }

        if (kt < ktend) __syncthreads();   // all waves done with tile before next DMA
    }

    // ---- partial epilogue: o[cg][dt][r] = O[q = cg*64 + w*16 + g*4 + r][d = dt*16 + l16] ----
    unsigned short* Op = Opart + (long)slot * 16384;
    #pragma unroll
    for (int cg = 0; cg < 2; ++cg) {
        #pragma unroll
        for (int dt = 0; dt < 8; ++dt) {
            #pragma unroll
            for (int r = 0; r < 4; ++r) {
                Op[(cg * 64 + w * 16 + g * 4 + r) * 128 + dt * 16 + l16] = f2bf(o[cg][dt][r]);
            }
        }
    }
    if (g == 0) {   // per-lane m/lsum correspond to q-row cg*64 + w*16 + l16
        #pragma unroll
        for (int cg = 0; cg < 2; ++cg) {
            Mpart[(long)slot * 128 + cg * 64 + w * 16 + l16] = m[cg];
            Lpart[(long)slot * 128 + cg * 64 + w * 16 + l16] = lsum[cg];
        }
    }
}

// ---------------- kernel 3: combine partials (r7 mapping, exp2 domain) ----------------
// grid (256, 4): x = qt*8 + eighth, y = b. Each block merges 16 rows of a 128-row q-tile.
__global__ __launch_bounds__(256) void combine_kernel(const unsigned short* __restrict__ Opart,
                                                      const float* __restrict__ Mpart,
                                                      const float* __restrict__ Lpart,
                                                      float* __restrict__ out) {
    __shared__ float coeff[16][16];
    __shared__ float invL[16];

    const int qt = blockIdx.x >> 3, qq = blockIdx.x & 7, b = blockIdx.y;
    const int h = qt >> 1;
    const int nc = h + 1;
    const int sbase = (qt & 1) ? (h + 1) * (h + 1) : h * (h + 1);
    const int slot0 = b * CPB + sbase;
    const int r0 = qq * 16;

    const int tid = threadIdx.x;
    if (tid < 16) {
        float mg = -INFINITY;
        for (int c = 0; c < nc; ++c)
            mg = fmaxf(mg, Mpart[(long)(slot0 + c) * 128 + r0 + tid]);
        float L = 0.f;
        for (int c = 0; c < nc; ++c) {
            float co = exp2f(Mpart[(long)(slot0 + c) * 128 + r0 + tid] - mg);
            coeff[c][tid] = co;
            L += co * Lpart[(long)(slot0 + c) * 128 + r0 + tid];
        }
        invL[tid] = 1.f / L;
    }
    __syncthreads();

    const int e0 = tid * 8;
    const int r = e0 >> 7;
    float acc[8];
    #pragma unroll
    for (int k = 0; k < 8; ++k) acc[k] = 0.f;
    for (int c = 0; c < nc; ++c) {
        short8 v = *reinterpret_cast<const short8*>(Opart + (long)(slot0 + c) * 16384 + r0 * 128 + e0);
        const float co = coeff[c][r];
        #pragma unroll
        for (int k = 0; k < 8; ++k)
            acc[k] += co * bf2f((unsigned short)v[k]);
    }
    const float s = invL[r];
    float4v o0, o1;
    o0[0] = acc[0] * s; o0[1] = acc[1] * s; o0[2] = acc[2] * s; o0[3] = acc[3] * s;
    o1[0] = acc[4] * s; o1[1] = acc[5] * s; o1[2] = acc[6] * s; o1[3] = acc[7] * s;
    float* dst = out + ((long)b * S_ + qt * 128 + r0) * 128 + e0;
    *reinterpret_cast<float4v*>(dst) = o0;
    *reinterpret_cast<float4v*>(dst + 4) = o1;
}

extern "C" void kernel_launch(void* const* d_in, const int* in_sizes, int n_in,
                              void* d_out, int out_size, void* d_ws, size_t ws_size,
                              hipStream_t stream) {
    (void)in_sizes; (void)n_in; (void)out_size; (void)ws_size;
    const float* x  = (const float*)d_in[0];
    const float* Wq = (const float*)d_in[1];
    const float* Wk = (const float*)d_in[2];
    const float* Wv = (const float*)d_in[3];
    float* out = (float*)d_out;

    char* ws = (char*)d_ws;
    const size_t MB4 = (size_t)16384 * 128 * 2;         // 4 MiB per bf16 tensor
    unsigned short* Qb = (unsigned short*)(ws);
    unsigned short* Kb = (unsigned short*)(ws + MB4);
    unsigned short* Vt = (unsigned short*)(ws + 2 * MB4);
    unsigned short* Wb = (unsigned short*)(ws + 3 * MB4);          // 96 KiB
    unsigned short* Opart = (unsigned short*)(ws + 3 * MB4 + (1 << 20));   // 1088*32KiB
    float* Mpart = (float*)(ws + 3 * MB4 + (1 << 20) + (size_t)NSLOT * 16384 * 2);
    float* Lpart = Mpart + (size_t)NSLOT * 128;

    wconv_kernel<<<192, 256, 0, stream>>>(Wq, Wk, Wv, Wb);
    qkv_kernel<<<dim3(256, 3), 256, 0, stream>>>(x, Wb, Qb, Kb, Vt);
    attn_kernel<<<NSLOT, 256, 0, stream>>>(Qb, Kb, Vt, Opart, Mpart, Lpart);
    combine_kernel<<<dim3(256, 4), 256, 0, stream>>>(Opart, Mpart, Lpart, out);
}